// Round 1
// baseline (176.991 us; speedup 1.0000x reference)
//
#include <hip/hip_runtime.h>
#include <stdint.h>

// ---------------------------------------------------------------------------
// UnifiedEnergyFunction: total/hopfield/consistency/regularization scalars.
//   hopfield = mean_b( -logsumexp_n( z[b,:] . M[n,:] ) )   (beta = 1)
//   consistency = mean_b ||z - z_next||^2                  (alpha = 1)
//   regularization = 0.01 * mean_b ||z||^2
// Strategy: bf16 MFMA GEMM (16x16x32) + online logsumexp, flash style.
// ---------------------------------------------------------------------------

typedef __attribute__((ext_vector_type(8))) short short8;
typedef __attribute__((ext_vector_type(4))) float f32x4;

#define N_PAT  65536
#define D_DIM  256
#define B_ROWS 4096
#define NSPLIT 16                 // n-splits (2 per XCD -> 4MB M range per XCD L2)
#define BBLK   128                // b rows per block
#define NTILE  64                 // n rows per LDS tile
#define NRANGE (N_PAT / NSPLIT)   // 4096
#define NITER  (NRANGE / NTILE)   // 64

// workspace layout (bytes)
#define WS_M_OFF   ((size_t)0)
#define WS_M_BYTES ((size_t)N_PAT * D_DIM * 2)     // 32 MB bf16 patterns
#define WS_Z_OFF   (WS_M_OFF + WS_M_BYTES)
#define WS_Z_BYTES ((size_t)B_ROWS * D_DIM * 2)    // 2 MB bf16 z
#define WS_LSE_OFF (WS_Z_OFF + WS_Z_BYTES)
#define WS_LSE_BYTES ((size_t)B_ROWS * NSPLIT * 8) // float2 per (b, nsplit)
#define WS_CSS_OFF (WS_LSE_OFF + WS_LSE_BYTES)
#define WS_ZSS_OFF (WS_CSS_OFF + (size_t)512 * 4)

__device__ __forceinline__ short f2bf(float f) {
  // round-to-nearest-even f32 -> bf16 (inputs are finite ~N(0,1))
  uint32_t u = __float_as_uint(f);
  uint32_t r = (u + 0x7fffu + ((u >> 16) & 1u)) >> 16;
  return (short)(r & 0xffffu);
}

typedef __attribute__((address_space(3))) uint32_t lds_u32;
typedef __attribute__((address_space(1))) uint32_t glb_u32;
__device__ __forceinline__ void load_lds16(const void* g, void* l) {
  // per-lane global source, wave-uniform LDS dest + lane*16 (HW behavior)
  __builtin_amdgcn_global_load_lds((const glb_u32*)g, (lds_u32*)l, 16, 0, 0);
}

__device__ __forceinline__ float waveRedAdd(float v) {
  #pragma unroll
  for (int o = 32; o > 0; o >>= 1) v += __shfl_down(v, o, 64);
  return v;  // valid in lane 0
}

// ---------------------------------------------------------------- kernel A1
__global__ void convert_m_kernel(const float* __restrict__ src, short* __restrict__ dst) {
  int64_t i = (int64_t)blockIdx.x * 256 + threadIdx.x;
  const int64_t n8 = (int64_t)N_PAT * D_DIM / 8;
  const int64_t stride = (int64_t)gridDim.x * 256;
  for (; i < n8; i += stride) {
    const float4 a = *(const float4*)(src + i * 8);
    const float4 b = *(const float4*)(src + i * 8 + 4);
    float v[8] = {a.x, a.y, a.z, a.w, b.x, b.y, b.z, b.w};
    short8 o;
    #pragma unroll
    for (int j = 0; j < 8; ++j) o[j] = f2bf(v[j]);
    *(short8*)(dst + i * 8) = o;
  }
}

// ---------------------------------------------------------------- kernel A2
// convert z -> bf16, and per-block partial sums of ||z-zn||^2 and ||z||^2
__global__ void prep_z_kernel(const float* __restrict__ z, const float* __restrict__ zn,
                              short* __restrict__ zbf, float* __restrict__ css,
                              float* __restrict__ zss) {
  int t = blockIdx.x * 256 + threadIdx.x;  // 512 blocks x 256 = exactly B*D/8
  const float* az = z + (size_t)t * 8;
  const float* an = zn + (size_t)t * 8;
  float4 z0 = *(const float4*)(az), z1 = *(const float4*)(az + 4);
  float4 n0 = *(const float4*)(an), n1 = *(const float4*)(an + 4);
  float zv[8] = {z0.x, z0.y, z0.z, z0.w, z1.x, z1.y, z1.z, z1.w};
  float nv[8] = {n0.x, n0.y, n0.z, n0.w, n1.x, n1.y, n1.z, n1.w};
  short8 o;
  float cs = 0.f, zs = 0.f;
  #pragma unroll
  for (int j = 0; j < 8; ++j) {
    o[j] = f2bf(zv[j]);
    float d = zv[j] - nv[j];
    cs += d * d;
    zs += zv[j] * zv[j];
  }
  *(short8*)(zbf + (size_t)t * 8) = o;

  __shared__ float rc[4], rz[4];
  cs = waveRedAdd(cs);
  zs = waveRedAdd(zs);
  int w = threadIdx.x >> 6, lane = threadIdx.x & 63;
  if (lane == 0) { rc[w] = cs; rz[w] = zs; }
  __syncthreads();
  if (threadIdx.x == 0) {
    css[blockIdx.x] = rc[0] + rc[1] + rc[2] + rc[3];
    zss[blockIdx.x] = rz[0] + rz[1] + rz[2] + rz[3];
  }
}

// ---------------------------------------------------------------- kernel B
// Flash-LSE: per block, 128 b-rows x 4096-n slice. Swapped-operand MFMA:
// D[i=n][j=b] = M_tile x z^T. Each wave owns 32 b's (z frags hoisted in regs),
// all 64 n of the current tile. Online (m, s) per b; partial out per n-split.
__global__ __launch_bounds__(256, 2) void lse_kernel(const short* __restrict__ Mbf,
                                                     const short* __restrict__ zbf,
                                                     float2* __restrict__ lsep) {
  __shared__ short mt[2][NTILE * D_DIM];  // 2 x 32KB, rows of 512B, XOR-swizzled content

  const int bid = blockIdx.x;             // 512 blocks
  const int xcd = bid & 7;                // dispatch round-robins XCDs
  const int g = bid >> 3;                 // 0..63
  const int bblk = g & 31;
  const int half = g >> 5;                // 0..1
  const int nsplit = xcd * 2 + half;      // both halves of an XCD share a 4MB M range

  const int tid = threadIdx.x;
  const int w = tid >> 6;
  const int lane = tid & 63;
  const int l15 = lane & 15;
  const int grp = lane >> 4;

  const char* msrc_base =
      (const char*)(Mbf + ((size_t)nsplit * NRANGE) * D_DIM);

  // stage one 64-row M tile (32KB) into LDS buf; linear dest, inverse-swizzled src
  auto stageM = [&](int it, int buf) {
    const char* src = msrc_base + (size_t)it * NTILE * D_DIM * 2;
    char* dst = (char*)&mt[buf][0];
    #pragma unroll
    for (int i = 0; i < 8; ++i) {
      int c = w * 8 + i;                    // 1KB chunk id (32 chunks, 4 waves)
      int d = c * 1024 + lane * 16;         // linear dest byte offset of this lane
      int s = d ^ (((d >> 9) & 7) << 4);    // involution: same XOR as read side
      load_lds16(src + s, dst + c * 1024);  // dest = uniform chunk base (+lane*16 by HW)
    }
  };

  stageM(0, 0);

  // hoist z fragments: 2 b-subtiles x 8 k-chunks, straight from global (one-time)
  short8 zf[2][8];
  const int brow0 = bblk * BBLK + w * 32;
  #pragma unroll
  for (int bt = 0; bt < 2; ++bt) {
    #pragma unroll
    for (int kc = 0; kc < 8; ++kc) {
      int row = brow0 + bt * 16 + l15;
      zf[bt][kc] = *(const short8*)(zbf + (size_t)row * D_DIM + kc * 32 + grp * 8);
    }
  }

  __syncthreads();  // drains vmcnt(0): tile 0 staged

  float mrun[2] = {-INFINITY, -INFINITY};
  float ssum[2] = {0.f, 0.f};
  const f32x4 zero4 = {0.f, 0.f, 0.f, 0.f};
  int cur = 0;

  for (int it = 0; it < NITER; ++it) {
    if (it + 1 < NITER) stageM(it + 1, cur ^ 1);  // prefetch next tile (T3-minimal)

    f32x4 acc[4][2];
    #pragma unroll
    for (int nt = 0; nt < 4; ++nt)
      #pragma unroll
      for (int bt = 0; bt < 2; ++bt) acc[nt][bt] = zero4;

    const char* tile = (const char*)&mt[cur][0];
    #pragma unroll
    for (int kc = 0; kc < 8; ++kc) {
      short8 mf[4];
      #pragma unroll
      for (int nt = 0; nt < 4; ++nt) {
        int row = nt * 16 + l15;
        int a = row * 512 + kc * 64 + grp * 16;
        a ^= ((row & 7) << 4);              // swizzled read (matches staged content)
        mf[nt] = *(const short8*)(tile + a);
      }
      #pragma unroll
      for (int nt = 0; nt < 4; ++nt)
        #pragma unroll
        for (int bt = 0; bt < 2; ++bt)
          acc[nt][bt] = __builtin_amdgcn_mfma_f32_16x16x32_bf16(mf[nt], zf[bt][kc],
                                                                acc[nt][bt], 0, 0, 0);
    }

    // online-LSE epilogue: per b (col = lane&15), reduce 64 n's of this tile
    #pragma unroll
    for (int bt = 0; bt < 2; ++bt) {
      float tmax = -INFINITY;
      #pragma unroll
      for (int nt = 0; nt < 4; ++nt)
        #pragma unroll
        for (int q = 0; q < 4; ++q) tmax = fmaxf(tmax, acc[nt][bt][q]);
      tmax = fmaxf(tmax, __shfl_xor(tmax, 16, 64));
      tmax = fmaxf(tmax, __shfl_xor(tmax, 32, 64));
      float mnew = fmaxf(mrun[bt], tmax);
      float s = ssum[bt] * __expf(mrun[bt] - mnew);  // exp(-inf)=0 on first tile
      #pragma unroll
      for (int nt = 0; nt < 4; ++nt)
        #pragma unroll
        for (int q = 0; q < 4; ++q) s += __expf(acc[nt][bt][q] - mnew);
      ssum[bt] = s;
      mrun[bt] = mnew;
    }

    __syncthreads();  // all waves done reading cur; next tile fully staged
    cur ^= 1;
  }

  // combine the 4 lane-groups' partial sums (they share mrun, synced every tile)
  #pragma unroll
  for (int bt = 0; bt < 2; ++bt) {
    ssum[bt] += __shfl_xor(ssum[bt], 16, 64);
    ssum[bt] += __shfl_xor(ssum[bt], 32, 64);
  }
  if (grp == 0) {
    #pragma unroll
    for (int bt = 0; bt < 2; ++bt) {
      int b = brow0 + bt * 16 + l15;
      lsep[(size_t)b * NSPLIT + nsplit] = make_float2(mrun[bt], ssum[bt]);
    }
  }
}

// ---------------------------------------------------------------- kernel C
__global__ void finalize_kernel(const float2* __restrict__ lsep, const float* __restrict__ css,
                                const float* __restrict__ zss, float* __restrict__ out) {
  __shared__ float r1[16], r2[16], r3[16];
  int tid = threadIdx.x;  // 1024
  float sum_lse = 0.f;
  for (int r = tid; r < B_ROWS; r += 1024) {
    float2 v[NSPLIT];
    float mm = -INFINITY;
    #pragma unroll
    for (int i = 0; i < NSPLIT; ++i) {
      v[i] = lsep[(size_t)r * NSPLIT + i];
      mm = fmaxf(mm, v[i].x);
    }
    float S = 0.f;
    #pragma unroll
    for (int i = 0; i < NSPLIT; ++i) S += v[i].y * __expf(v[i].x - mm);
    sum_lse += mm + logf(S);
  }
  float cs = 0.f, zs = 0.f;
  if (tid < 512) { cs = css[tid]; zs = zss[tid]; }

  sum_lse = waveRedAdd(sum_lse);
  cs = waveRedAdd(cs);
  zs = waveRedAdd(zs);
  int w = tid >> 6, lane = tid & 63;
  if (lane == 0) { r1[w] = sum_lse; r2[w] = cs; r3[w] = zs; }
  __syncthreads();
  if (tid == 0) {
    float sl = 0.f, sc = 0.f, sz = 0.f;
    #pragma unroll
    for (int i = 0; i < 16; ++i) { sl += r1[i]; sc += r2[i]; sz += r3[i]; }
    float hop = -sl / (float)B_ROWS;
    float cons = sc / (float)B_ROWS;
    float reg = 0.01f * sz / (float)B_ROWS;
    out[0] = hop + cons + reg;
    out[1] = hop;
    out[2] = cons;
    out[3] = reg;
  }
}

// ---------------------------------------------------------------------------
extern "C" void kernel_launch(void* const* d_in, const int* in_sizes, int n_in,
                              void* d_out, int out_size, void* d_ws, size_t ws_size,
                              hipStream_t stream) {
  (void)in_sizes; (void)n_in; (void)out_size; (void)ws_size;
  const float* z  = (const float*)d_in[0];
  const float* zn = (const float*)d_in[1];
  const float* M  = (const float*)d_in[2];
  char* ws = (char*)d_ws;
  short* Mbf = (short*)(ws + WS_M_OFF);
  short* zbf = (short*)(ws + WS_Z_OFF);
  float2* lsep = (float2*)(ws + WS_LSE_OFF);
  float* css = (float*)(ws + WS_CSS_OFF);
  float* zss = (float*)(ws + WS_ZSS_OFF);

  convert_m_kernel<<<2048, 256, 0, stream>>>(M, Mbf);
  prep_z_kernel<<<512, 256, 0, stream>>>(z, zn, zbf, css, zss);
  lse_kernel<<<512, 256, 0, stream>>>(Mbf, zbf, lsep);
  finalize_kernel<<<1, 1024, 0, stream>>>(lsep, css, zss, (float*)d_out);
}